// Round 8
// baseline (1710.465 us; speedup 1.0000x reference)
//
#include <hip/hip_runtime.h>
#include <hip/hip_bf16.h>
#include <math.h>

#define NEG_SLOPE 0.2f
typedef __hip_bfloat16 bf16;
typedef __attribute__((ext_vector_type(8))) unsigned short ushort8;

// XOR swizzle: logical float-column c -> physical column (breaks stride-32 conflicts)
#define SWZ(c) ((c) ^ ((((c) >> 5) & 7) << 2))

__device__ __forceinline__ float bf2f(unsigned short u) {
    return __uint_as_float(((unsigned)u) << 16);
}

__device__ __forceinline__ void edge_sd(const int* __restrict__ ei, int E, int e, int& s, int& d) {
    if (e < E) { s = ei[e]; d = ei[E + e]; }
    else { s = e - E; d = s; }  // self-loop
}

// ================= CSR build =================
__global__ void k_hist(const int* __restrict__ ei, int E, int Etot, int* __restrict__ deg)
{
    int e = blockIdx.x * blockDim.x + threadIdx.x;
    if (e >= Etot) return;
    int s, d; edge_sd(ei, E, e, s, d);
    atomicAdd(&deg[d], 1);
}

__global__ __launch_bounds__(1024) void k_scan(const int* __restrict__ deg,
                                               int* __restrict__ rs, int N)
{
    __shared__ int part[1024];
    int t = threadIdx.x;
    int chunk = (N + 1023) >> 10;
    int b = t * chunk, e = min(b + chunk, N);
    int s = 0;
    for (int i = b; i < e; ++i) s += deg[i];
    part[t] = s;
    __syncthreads();
    for (int off = 1; off < 1024; off <<= 1) {
        int v = (t >= off) ? part[t - off] : 0;
        __syncthreads();
        part[t] += v;
        __syncthreads();
    }
    int excl = (t == 0) ? 0 : part[t - 1];
    for (int i = b; i < e; ++i) { rs[i] = excl; excl += deg[i]; }
    if (t == 1023) rs[N] = part[1023];
}

__global__ void k_fill(const int* __restrict__ ei, int E, int Etot,
                       const int* __restrict__ rs, int* __restrict__ cur,
                       int* __restrict__ csr_src)
{
    int e = blockIdx.x * blockDim.x + threadIdx.x;
    if (e >= Etot) return;
    int s, d; edge_sd(ei, E, e, s, d);
    int pos = rs[d] + atomicAdd(&cur[d], 1);
    csr_src[pos] = s;
}

// ================= Layer 1 =================
// wboth[k][c16]: c<8 -> src-fold head c ; c>=8 -> dst-fold head c-8
__global__ __launch_bounds__(512) void k_prew(
    const float* __restrict__ W1, const float* __restrict__ a_src,
    const float* __restrict__ a_dst, float* __restrict__ wboth)
{
    int t = threadIdx.x;           // 512 = 64 k x 8 h
    int k = t >> 3, h = t & 7;
    float s = 0.f, d = 0.f;
    const float* wr = W1 + k * 512 + h * 64;
    const float* as = a_src + h * 64;
    const float* ad = a_dst + h * 64;
#pragma unroll
    for (int c = 0; c < 64; ++c) { s += wr[c] * as[c]; d += wr[c] * ad[c]; }
    wboth[k * 16 + h] = s;
    wboth[k * 16 + 8 + h] = d;
}

// per-node attention terms: 256 thr = 4 waves x 4 nodes x 16 lanes
__global__ __launch_bounds__(256) void k_alpha1n(
    const float* __restrict__ x, const float* __restrict__ wboth,
    float* __restrict__ asrc, float* __restrict__ adst, int N)
{
    __shared__ float wl[16][64];   // transposed: wl[c][k]
    int t = threadIdx.x;
    for (int i = t; i < 1024; i += 256) {
        int k = i >> 4, c = i & 15;
        wl[c][k] = wboth[i];
    }
    __syncthreads();
    int wave = t >> 6, lane = t & 63;
    int nsub = lane >> 4, ksub = lane & 15;
    int n = blockIdx.x * 16 + wave * 4 + nsub;
    bool valid = (n < N);
    float xv[4];
#pragma unroll
    for (int i = 0; i < 4; ++i)
        xv[i] = valid ? x[(size_t)n * 64 + i * 16 + ksub] : 0.f;
    float acc[16];
#pragma unroll
    for (int c = 0; c < 16; ++c) acc[c] = 0.f;
#pragma unroll
    for (int i = 0; i < 4; ++i) {
        float xi = xv[i];
        int k = i * 16 + ksub;
#pragma unroll
        for (int c = 0; c < 16; ++c) acc[c] += xi * wl[c][k];
    }
#pragma unroll
    for (int c = 0; c < 16; ++c) {
        acc[c] += __shfl_xor(acc[c], 1, 16);
        acc[c] += __shfl_xor(acc[c], 2, 16);
        acc[c] += __shfl_xor(acc[c], 4, 16);
        acc[c] += __shfl_xor(acc[c], 8, 16);
    }
    if (valid) {
        if (ksub < 8) asrc[n * 8 + ksub] = acc[ksub];
        else          adst[n * 8 + (ksub - 8)] = acc[ksub];
    }
}

// softmax layer1 (2-pass, online max+sum; stores UNNORMALIZED p and 1/denom)
// wave per node; lane = (j0 = lane>>3, head h = lane&7)
__global__ __launch_bounds__(256) void k_sm1(
    const int* __restrict__ rs, const int* __restrict__ csr_src,
    const float* __restrict__ asrc, const float* __restrict__ adst,
    float* __restrict__ aE, float* __restrict__ invden, int N)
{
    int node = blockIdx.x * 4 + (threadIdx.x >> 6);
    if (node >= N) return;
    int lane = threadIdx.x & 63;
    int h = lane & 7, j0 = lane >> 3;
    int base = rs[node], deg = rs[node + 1] - base;
    float ad = adst[node * 8 + h];
    float m = -1e30f, s = 0.f;
    for (int j = j0; j < deg; j += 8) {
        int src = csr_src[base + j];
        float el = asrc[src * 8 + h] + ad;
        el = el >= 0.f ? el : NEG_SLOPE * el;
        if (el > m) { s = s * __expf(m - el) + 1.f; m = el; }
        else        { s += __expf(el - m); }
    }
#pragma unroll
    for (int off = 8; off < 64; off <<= 1) {
        float m2 = __shfl_xor(m, off, 64);
        float s2 = __shfl_xor(s, off, 64);
        float M = fmaxf(m, m2);
        s = s * __expf(m - M) + s2 * __expf(m2 - M);
        m = M;
    }
    if (lane < 8) invden[node * 8 + lane] = 1.f / (s + 1e-16f);
    for (int j = j0; j < deg; j += 8) {
        int src = csr_src[base + j];
        float el = asrc[src * 8 + h] + ad;
        el = el >= 0.f ? el : NEG_SLOPE * el;
        aE[(size_t)(base + j) * 8 + h] = __expf(el - m);
    }
}

// ===== fused: x-space aggregate (wave per node) + per-head GEMM + bias + ELU =====
// phase 1: wave m = node n0+m; lane = k; acc[8] = all heads; tail scales by invden.
//   z staged TRANSPOSED in LDS: zs[m][h*64+k] (consecutive-lane writes, conflict-free).
// phase 2: wave w has h = w; zs reads are wave-uniform broadcast float4 (b128).
#define NPB 8
__global__ __launch_bounds__(512) void k_agg_gemm1(
    const int* __restrict__ rs, const int* __restrict__ csr_src,
    const float* __restrict__ aE, const float* __restrict__ invden,
    const float* __restrict__ x,
    const float* __restrict__ W1, const float* __restrict__ b1,
    bf16* __restrict__ y, int N)
{
    __shared__ float zs[NPB][512];   // 16 KB
    int t = threadIdx.x;
    int wave = t >> 6, lane = t & 63;
    int n = blockIdx.x * NPB + wave;

    if (n < N) {
        int base = rs[n], deg = rs[n + 1] - base;
        float acc[8];
#pragma unroll
        for (int h = 0; h < 8; ++h) acc[h] = 0.f;
        for (int j0 = 0; j0 < deg; j0 += 64) {
            int cnt = min(64, deg - j0);
            int sidx = csr_src[base + j0 + min(lane, cnt - 1)];
#pragma unroll 2
            for (int j = 0; j < cnt; ++j) {
                int s = __shfl(sidx, j, 64);
                float xv = x[(size_t)s * 64 + lane];
                const float4* ap = (const float4*)(aE + (size_t)(base + j0 + j) * 8);
                float4 a0 = ap[0], a1 = ap[1];
                acc[0] += a0.x * xv; acc[1] += a0.y * xv;
                acc[2] += a0.z * xv; acc[3] += a0.w * xv;
                acc[4] += a1.x * xv; acc[5] += a1.y * xv;
                acc[6] += a1.z * xv; acc[7] += a1.w * xv;
            }
        }
        const float4* ivp = (const float4*)(invden + (size_t)n * 8);
        float4 iv0 = ivp[0], iv1 = ivp[1];
        acc[0] *= iv0.x; acc[1] *= iv0.y; acc[2] *= iv0.z; acc[3] *= iv0.w;
        acc[4] *= iv1.x; acc[5] *= iv1.y; acc[6] *= iv1.z; acc[7] *= iv1.w;
#pragma unroll
        for (int h = 0; h < 8; ++h) zs[wave][h * 64 + lane] = acc[h];
    } else {
#pragma unroll
        for (int h = 0; h < 8; ++h) zs[wave][h * 64 + lane] = 0.f;
    }
    __syncthreads();

    // phase 2: y[n0+m][t] = elu( sum_k zs[m][h*64+k] * W1[k*512+t] + b1[t] ),  h = t>>6
    int n0 = blockIdx.x * NPB;
    int h = t >> 6;
    float acc2[NPB];
#pragma unroll
    for (int m = 0; m < NPB; ++m) acc2[m] = 0.f;
#pragma unroll
    for (int k4 = 0; k4 < 16; ++k4) {
        float w0 = W1[(k4 * 4 + 0) * 512 + t];
        float w1 = W1[(k4 * 4 + 1) * 512 + t];
        float w2 = W1[(k4 * 4 + 2) * 512 + t];
        float w3 = W1[(k4 * 4 + 3) * 512 + t];
#pragma unroll
        for (int m = 0; m < NPB; ++m) {
            float4 zv = *(const float4*)&zs[m][h * 64 + k4 * 4];
            acc2[m] += zv.x * w0 + zv.y * w1 + zv.z * w2 + zv.w * w3;
        }
    }
    float bias = b1[t];
#pragma unroll
    for (int m = 0; m < NPB; ++m) {
        int nn = n0 + m;
        if (nn < N) {
            float v = acc2[m] + bias;
            v = v > 0.f ? v : __expf(v) - 1.f;
            y[(size_t)nn * 512 + t] = __float2bfloat16(v);
        }
    }
}

// ================= Layer 2 =================
// h2 = y @ W2 (+ fused attention dots). 512 thr = 8 waves x 4 nodes x 16 lanes.
// 64 nodes per block (2 passes) to amortize W2 staging; W2t XOR-swizzled.
__global__ __launch_bounds__(512) void k_gemm2(
    const bf16* __restrict__ y, const float* __restrict__ W2,
    const float* __restrict__ a_src2, const float* __restrict__ a_dst2,
    float* __restrict__ h2, float* __restrict__ asrc, float* __restrict__ adst, int N)
{
    __shared__ float W2t[17][512];
    __shared__ float a2s[34];
    int t = threadIdx.x;
    for (int i = t; i < 17 * 512; i += 512) {
        int c = i >> 9, k = i & 511;
        W2t[c][SWZ(k)] = W2[k * 17 + c];
    }
    if (t < 17) a2s[t] = a_src2[t];
    else if (t < 34) a2s[t] = a_dst2[t - 17];
    __syncthreads();

    int wave = t >> 6, lane = t & 63;
    int nsub = lane >> 4, ksub = lane & 15;
    int kx = ksub & 7;

#pragma unroll
    for (int pass = 0; pass < 2; ++pass) {
        int n = blockIdx.x * 64 + pass * 32 + wave * 4 + nsub;
        bool valid = (n < N);

        float yk[32];
        if (valid) {
            const ushort8* yr = (const ushort8*)(y + (size_t)n * 512 + ksub * 32);
#pragma unroll
            for (int v = 0; v < 4; ++v) {
                ushort8 u = yr[v];
#pragma unroll
                for (int j = 0; j < 8; ++j) yk[v * 8 + j] = bf2f(u[j]);
            }
        } else {
#pragma unroll
            for (int i = 0; i < 32; ++i) yk[i] = 0.f;
        }

        float acc[17];
#pragma unroll
        for (int c = 0; c < 17; ++c) {
            float a = 0.f;
#pragma unroll
            for (int v = 0; v < 8; ++v) {
                // physical chunk (v ^ kx) holds logical k-chunk v
                const float4 w = *(const float4*)&W2t[c][ksub * 32 + ((v ^ kx) << 2)];
                a += yk[v * 4 + 0] * w.x + yk[v * 4 + 1] * w.y
                   + yk[v * 4 + 2] * w.z + yk[v * 4 + 3] * w.w;
            }
            acc[c] = a;
        }
#pragma unroll
        for (int c = 0; c < 17; ++c) {
            acc[c] += __shfl_xor(acc[c], 1, 16);
            acc[c] += __shfl_xor(acc[c], 2, 16);
            acc[c] += __shfl_xor(acc[c], 4, 16);
            acc[c] += __shfl_xor(acc[c], 8, 16);
        }
        if (valid) {
            if (ksub < 16) h2[(size_t)n * 17 + ksub] = acc[ksub];
            if (ksub == 0) h2[(size_t)n * 17 + 16] = acc[16];
            if (ksub == 1) {
                float s = 0.f;
#pragma unroll
                for (int c = 0; c < 17; ++c) s += acc[c] * a2s[c];
                asrc[n] = s;
            }
            if (ksub == 2) {
                float d = 0.f;
#pragma unroll
                for (int c = 0; c < 17; ++c) d += acc[c] * a2s[17 + c];
                adst[n] = d;
            }
        }
    }
}

// softmax layer2 (2-pass online; stores UNNORMALIZED alpha and 1/denom)
__global__ __launch_bounds__(256) void k_sm2(
    const int* __restrict__ rs, const int* __restrict__ csr_src,
    const float* __restrict__ asrc, const float* __restrict__ adst,
    float* __restrict__ alpha, float* __restrict__ invden, int N)
{
    int node = blockIdx.x * 4 + (threadIdx.x >> 6);
    if (node >= N) return;
    int lane = threadIdx.x & 63;
    int base = rs[node], deg = rs[node + 1] - base;
    float ad = adst[node];
    float m = -1e30f, s = 0.f;
    for (int j = lane; j < deg; j += 64) {
        float el = asrc[csr_src[base + j]] + ad;
        el = el >= 0.f ? el : NEG_SLOPE * el;
        if (el > m) { s = s * __expf(m - el) + 1.f; m = el; }
        else        { s += __expf(el - m); }
    }
#pragma unroll
    for (int off = 1; off < 64; off <<= 1) {
        float m2 = __shfl_xor(m, off, 64);
        float s2 = __shfl_xor(s, off, 64);
        float M = fmaxf(m, m2);
        s = s * __expf(m - M) + s2 * __expf(m2 - M);
        m = M;
    }
    if (lane == 0) invden[node] = 1.f / (s + 1e-16f);
    for (int j = lane; j < deg; j += 64) {
        float el = asrc[csr_src[base + j]] + ad;
        el = el >= 0.f ? el : NEG_SLOPE * el;
        alpha[base + j] = __expf(el - m);
    }
}

// aggregate layer2 + invden + bias + log_softmax
__global__ __launch_bounds__(256) void k_out(
    const int* __restrict__ rs, const int* __restrict__ csr_src,
    const float* __restrict__ alpha, const float* __restrict__ invden,
    const float* __restrict__ h2,
    const float* __restrict__ b2, float* __restrict__ out, int N)
{
    int node = blockIdx.x * 4 + (threadIdx.x >> 6);
    if (node >= N) return;
    int lane = threadIdx.x & 63;
    int c = lane & 31, jsub = lane >> 5;
    int base = rs[node], end = rs[node + 1];
    float acc = 0.f;
    if (c < 17) {
        for (int p = base + jsub; p < end; p += 2) {
            int s = csr_src[p];
            acc += alpha[p] * h2[(size_t)s * 17 + c];
        }
    }
    acc += __shfl_xor(acc, 32, 64);  // combine the two edge halves
    acc *= invden[node];
    float logit = (c < 17) ? acc + b2[c] : -1e30f;
    float m = logit;
#pragma unroll
    for (int off = 1; off < 32; off <<= 1) m = fmaxf(m, __shfl_xor(m, off, 32));
    float p = (c < 17) ? __expf(logit - m) : 0.f;
    float ssum = p;
#pragma unroll
    for (int off = 1; off < 32; off <<= 1) ssum += __shfl_xor(ssum, off, 32);
    if (c < 17 && jsub == 0) out[(size_t)node * 17 + c] = logit - m - logf(ssum);
}

extern "C" void kernel_launch(void* const* d_in, const int* in_sizes, int n_in,
                              void* d_out, int out_size, void* d_ws, size_t ws_size,
                              hipStream_t stream)
{
    const float* x      = (const float*)d_in[0];
    const int*   ei     = (const int*)d_in[1];
    const float* W1     = (const float*)d_in[2];
    const float* asrc1w = (const float*)d_in[3];
    const float* adst1w = (const float*)d_in[4];
    const float* b1     = (const float*)d_in[5];
    const float* W2     = (const float*)d_in[6];
    const float* asrc2w = (const float*)d_in[7];
    const float* adst2w = (const float*)d_in[8];
    const float* b2     = (const float*)d_in[9];
    float* out = (float*)d_out;

    const int N = in_sizes[0] / 64;
    const int E = in_sizes[1] / 2;
    const int Etot = N + E;

    // workspace layout
    float* ws = (float*)d_ws;
    size_t o = 0;
    bf16*  y      = (bf16*)(ws + o); o += (size_t)N * 256;   // N*512 bf16
    float* wboth  = ws + o; o += 1024;
    float* asrc1  = ws + o; o += (size_t)N * 8;
    float* adst1  = ws + o; o += (size_t)N * 8;
    float* aE1    = ws + o; o += (size_t)Etot * 8;
    float* ivd1   = ws + o; o += (size_t)N * 8;
    float* h2     = ws + o; o += (size_t)N * 17;
    float* asrc2  = ws + o; o += (size_t)N;
    float* adst2  = ws + o; o += (size_t)N;
    float* aE2    = ws + o; o += (size_t)Etot;
    float* ivd2   = ws + o; o += (size_t)N;
    int* deg      = (int*)(ws + o); o += (size_t)N;
    int* cur      = (int*)(ws + o); o += (size_t)N;
    int* rs       = (int*)(ws + o); o += (size_t)N + 1;
    int* csr_src  = (int*)(ws + o); o += (size_t)Etot;

    hipMemsetAsync(deg, 0, (size_t)N * 4, stream);
    hipMemsetAsync(cur, 0, (size_t)N * 4, stream);

    // CSR build
    {
        int blk = 256, g = (Etot + blk - 1) / blk;
        k_hist<<<g, blk, 0, stream>>>(ei, E, Etot, deg);
        k_scan<<<1, 1024, 0, stream>>>(deg, rs, N);
        k_fill<<<g, blk, 0, stream>>>(ei, E, Etot, rs, cur, csr_src);
    }

    // layer 1
    k_prew<<<1, 512, 0, stream>>>(W1, asrc1w, adst1w, wboth);
    k_alpha1n<<<(N + 15) / 16, 256, 0, stream>>>(x, wboth, asrc1, adst1, N);
    k_sm1<<<(N + 3) / 4, 256, 0, stream>>>(rs, csr_src, asrc1, adst1, aE1, ivd1, N);
    k_agg_gemm1<<<(N + NPB - 1) / NPB, 512, 0, stream>>>(rs, csr_src, aE1, ivd1, x, W1, b1, y, N);

    // layer 2
    k_gemm2<<<(N + 63) / 64, 512, 0, stream>>>(y, W2, asrc2w, adst2w, h2, asrc2, adst2, N);
    k_sm2<<<(N + 3) / 4, 256, 0, stream>>>(rs, csr_src, asrc2, adst2, aE2, ivd2, N);
    k_out<<<(N + 3) / 4, 256, 0, stream>>>(rs, csr_src, aE2, ivd2, h2, b2, out, N);
}

// Round 9
// 456.372 us; speedup vs baseline: 3.7480x; 3.7480x over previous
//
#include <hip/hip_runtime.h>
#include <hip/hip_bf16.h>
#include <math.h>

#define NEG_SLOPE 0.2f
typedef __hip_bfloat16 bf16;
typedef __attribute__((ext_vector_type(8))) unsigned short ushort8;

// XOR swizzle: logical float-column c -> physical column (breaks stride-32 conflicts)
#define SWZ(c) ((c) ^ ((((c) >> 5) & 7) << 2))

__device__ __forceinline__ float bf2f(unsigned short u) {
    return __uint_as_float(((unsigned)u) << 16);
}

__device__ __forceinline__ void edge_sd(const int* __restrict__ ei, int E, int e, int& s, int& d) {
    if (e < E) { s = ei[e]; d = ei[E + e]; }
    else { s = e - E; d = s; }  // self-loop
}

// ================= CSR build =================
__global__ void k_hist(const int* __restrict__ ei, int E, int Etot, int* __restrict__ deg)
{
    int e = blockIdx.x * blockDim.x + threadIdx.x;
    if (e >= Etot) return;
    int s, d; edge_sd(ei, E, e, s, d);
    atomicAdd(&deg[d], 1);
}

__global__ __launch_bounds__(1024) void k_scan(const int* __restrict__ deg,
                                               int* __restrict__ rs, int N)
{
    __shared__ int part[1024];
    int t = threadIdx.x;
    int chunk = (N + 1023) >> 10;
    int b = t * chunk, e = min(b + chunk, N);
    int s = 0;
    for (int i = b; i < e; ++i) s += deg[i];
    part[t] = s;
    __syncthreads();
    for (int off = 1; off < 1024; off <<= 1) {
        int v = (t >= off) ? part[t - off] : 0;
        __syncthreads();
        part[t] += v;
        __syncthreads();
    }
    int excl = (t == 0) ? 0 : part[t - 1];
    for (int i = b; i < e; ++i) { rs[i] = excl; excl += deg[i]; }
    if (t == 1023) rs[N] = part[1023];
}

__global__ void k_fill(const int* __restrict__ ei, int E, int Etot,
                       const int* __restrict__ rs, int* __restrict__ cur,
                       int* __restrict__ csr_src)
{
    int e = blockIdx.x * blockDim.x + threadIdx.x;
    if (e >= Etot) return;
    int s, d; edge_sd(ei, E, e, s, d);
    int pos = rs[d] + atomicAdd(&cur[d], 1);
    csr_src[pos] = s;
}

// ================= Layer 1 =================
// wboth[k][c16]: c<8 -> src-fold head c ; c>=8 -> dst-fold head c-8
__global__ __launch_bounds__(512) void k_prew(
    const float* __restrict__ W1, const float* __restrict__ a_src,
    const float* __restrict__ a_dst, float* __restrict__ wboth)
{
    int t = threadIdx.x;           // 512 = 64 k x 8 h
    int k = t >> 3, h = t & 7;
    float s = 0.f, d = 0.f;
    const float* wr = W1 + k * 512 + h * 64;
    const float* as = a_src + h * 64;
    const float* ad = a_dst + h * 64;
#pragma unroll
    for (int c = 0; c < 64; ++c) { s += wr[c] * as[c]; d += wr[c] * ad[c]; }
    wboth[k * 16 + h] = s;
    wboth[k * 16 + 8 + h] = d;
}

// per-node attention terms: 256 thr = 4 waves x 4 nodes x 16 lanes
__global__ __launch_bounds__(256) void k_alpha1n(
    const float* __restrict__ x, const float* __restrict__ wboth,
    float* __restrict__ asrc, float* __restrict__ adst, int N)
{
    __shared__ float wl[16][64];   // transposed: wl[c][k]
    int t = threadIdx.x;
    for (int i = t; i < 1024; i += 256) {
        int k = i >> 4, c = i & 15;
        wl[c][k] = wboth[i];
    }
    __syncthreads();
    int wave = t >> 6, lane = t & 63;
    int nsub = lane >> 4, ksub = lane & 15;
    int n = blockIdx.x * 16 + wave * 4 + nsub;
    bool valid = (n < N);
    float xv[4];
#pragma unroll
    for (int i = 0; i < 4; ++i)
        xv[i] = valid ? x[(size_t)n * 64 + i * 16 + ksub] : 0.f;
    float acc[16];
#pragma unroll
    for (int c = 0; c < 16; ++c) acc[c] = 0.f;
#pragma unroll
    for (int i = 0; i < 4; ++i) {
        float xi = xv[i];
        int k = i * 16 + ksub;
#pragma unroll
        for (int c = 0; c < 16; ++c) acc[c] += xi * wl[c][k];
    }
#pragma unroll
    for (int c = 0; c < 16; ++c) {
        acc[c] += __shfl_xor(acc[c], 1, 16);
        acc[c] += __shfl_xor(acc[c], 2, 16);
        acc[c] += __shfl_xor(acc[c], 4, 16);
        acc[c] += __shfl_xor(acc[c], 8, 16);
    }
    if (valid) {
        if (ksub < 8) asrc[n * 8 + ksub] = acc[ksub];
        else          adst[n * 8 + (ksub - 8)] = acc[ksub];
    }
}

// softmax layer1 (2-pass, online max+sum; stores UNNORMALIZED p and 1/denom)
// wave per node; lane = (j0 = lane>>3, head h = lane&7)
__global__ __launch_bounds__(256) void k_sm1(
    const int* __restrict__ rs, const int* __restrict__ csr_src,
    const float* __restrict__ asrc, const float* __restrict__ adst,
    float* __restrict__ aE, float* __restrict__ invden, int N)
{
    int node = blockIdx.x * 4 + (threadIdx.x >> 6);
    if (node >= N) return;
    int lane = threadIdx.x & 63;
    int h = lane & 7, j0 = lane >> 3;
    int base = rs[node], deg = rs[node + 1] - base;
    float ad = adst[node * 8 + h];
    float m = -1e30f, s = 0.f;
    for (int j = j0; j < deg; j += 8) {
        int src = csr_src[base + j];
        float el = asrc[src * 8 + h] + ad;
        el = el >= 0.f ? el : NEG_SLOPE * el;
        if (el > m) { s = s * __expf(m - el) + 1.f; m = el; }
        else        { s += __expf(el - m); }
    }
#pragma unroll
    for (int off = 8; off < 64; off <<= 1) {
        float m2 = __shfl_xor(m, off, 64);
        float s2 = __shfl_xor(s, off, 64);
        float M = fmaxf(m, m2);
        s = s * __expf(m - M) + s2 * __expf(m2 - M);
        m = M;
    }
    if (lane < 8) invden[node * 8 + lane] = 1.f / (s + 1e-16f);
    for (int j = j0; j < deg; j += 8) {
        int src = csr_src[base + j];
        float el = asrc[src * 8 + h] + ad;
        el = el >= 0.f ? el : NEG_SLOPE * el;
        aE[(size_t)(base + j) * 8 + h] = __expf(el - m);
    }
}

// ===== fused: x-space aggregate (wave per node) + per-head GEMM + bias + ELU =====
// phase 1: wave m = node n0+m; lane = k; acc[8] = all heads; tail scales by invden.
//   z staged TRANSPOSED in LDS: zs[m][h*64+k] (consecutive-lane writes, conflict-free).
// phase 2: R7-PROVEN loop shape — scalar b32 broadcast zs reads, coalesced W1 rows.
//   (float4/reg-tile variants spill to scratch: R5, R8 — do not reintroduce.)
#define NPB 8
__global__ __launch_bounds__(512) void k_agg_gemm1(
    const int* __restrict__ rs, const int* __restrict__ csr_src,
    const float* __restrict__ aE, const float* __restrict__ invden,
    const float* __restrict__ x,
    const float* __restrict__ W1, const float* __restrict__ b1,
    bf16* __restrict__ y, int N)
{
    __shared__ float zs[NPB][512];   // 16 KB
    int t = threadIdx.x;
    int wave = t >> 6, lane = t & 63;
    int n = blockIdx.x * NPB + wave;

    if (n < N) {
        int base = rs[n], deg = rs[n + 1] - base;
        float acc[8];
#pragma unroll
        for (int h = 0; h < 8; ++h) acc[h] = 0.f;
        for (int j0 = 0; j0 < deg; j0 += 64) {
            int cnt = min(64, deg - j0);
            int sidx = csr_src[base + j0 + min(lane, cnt - 1)];
#pragma unroll 2
            for (int j = 0; j < cnt; ++j) {
                int s = __shfl(sidx, j, 64);
                float xv = x[(size_t)s * 64 + lane];
                const float4* ap = (const float4*)(aE + (size_t)(base + j0 + j) * 8);
                float4 a0 = ap[0], a1 = ap[1];
                acc[0] += a0.x * xv; acc[1] += a0.y * xv;
                acc[2] += a0.z * xv; acc[3] += a0.w * xv;
                acc[4] += a1.x * xv; acc[5] += a1.y * xv;
                acc[6] += a1.z * xv; acc[7] += a1.w * xv;
            }
        }
        const float4* ivp = (const float4*)(invden + (size_t)n * 8);
        float4 iv0 = ivp[0], iv1 = ivp[1];
        acc[0] *= iv0.x; acc[1] *= iv0.y; acc[2] *= iv0.z; acc[3] *= iv0.w;
        acc[4] *= iv1.x; acc[5] *= iv1.y; acc[6] *= iv1.z; acc[7] *= iv1.w;
#pragma unroll
        for (int h = 0; h < 8; ++h) zs[wave][h * 64 + lane] = acc[h];
    } else {
#pragma unroll
        for (int h = 0; h < 8; ++h) zs[wave][h * 64 + lane] = 0.f;
    }
    __syncthreads();

    // phase 2: y[n0+m][t] = elu( sum_k zs[m][h*64+k] * W1[k*512+t] + b1[t] ),  h = t>>6
    int n0 = blockIdx.x * NPB;
    int h = t >> 6;
    float acc2[NPB];
#pragma unroll
    for (int m = 0; m < NPB; ++m) acc2[m] = 0.f;
#pragma unroll 8
    for (int k = 0; k < 64; ++k) {
        float w = W1[k * 512 + t];
#pragma unroll
        for (int m = 0; m < NPB; ++m) acc2[m] += zs[m][h * 64 + k] * w;
    }
    float bias = b1[t];
#pragma unroll
    for (int m = 0; m < NPB; ++m) {
        int nn = n0 + m;
        if (nn < N) {
            float v = acc2[m] + bias;
            v = v > 0.f ? v : __expf(v) - 1.f;
            y[(size_t)nn * 512 + t] = __float2bfloat16(v);
        }
    }
}

// ================= Layer 2 =================
// h2 = y @ W2 (+ fused attention dots). 512 thr = 8 waves x 4 nodes x 16 lanes.
// 64 nodes per block (2 passes) to amortize W2 staging; W2t XOR-swizzled.
__global__ __launch_bounds__(512) void k_gemm2(
    const bf16* __restrict__ y, const float* __restrict__ W2,
    const float* __restrict__ a_src2, const float* __restrict__ a_dst2,
    float* __restrict__ h2, float* __restrict__ asrc, float* __restrict__ adst, int N)
{
    __shared__ float W2t[17][512];
    __shared__ float a2s[34];
    int t = threadIdx.x;
    for (int i = t; i < 17 * 512; i += 512) {
        int c = i >> 9, k = i & 511;
        W2t[c][SWZ(k)] = W2[k * 17 + c];
    }
    if (t < 17) a2s[t] = a_src2[t];
    else if (t < 34) a2s[t] = a_dst2[t - 17];
    __syncthreads();

    int wave = t >> 6, lane = t & 63;
    int nsub = lane >> 4, ksub = lane & 15;
    int kx = ksub & 7;

#pragma unroll
    for (int pass = 0; pass < 2; ++pass) {
        int n = blockIdx.x * 64 + pass * 32 + wave * 4 + nsub;
        bool valid = (n < N);

        float yk[32];
        if (valid) {
            const ushort8* yr = (const ushort8*)(y + (size_t)n * 512 + ksub * 32);
#pragma unroll
            for (int v = 0; v < 4; ++v) {
                ushort8 u = yr[v];
#pragma unroll
                for (int j = 0; j < 8; ++j) yk[v * 8 + j] = bf2f(u[j]);
            }
        } else {
#pragma unroll
            for (int i = 0; i < 32; ++i) yk[i] = 0.f;
        }

        float acc[17];
#pragma unroll
        for (int c = 0; c < 17; ++c) {
            float a = 0.f;
#pragma unroll
            for (int v = 0; v < 8; ++v) {
                // physical chunk (v ^ kx) holds logical k-chunk v
                const float4 w = *(const float4*)&W2t[c][ksub * 32 + ((v ^ kx) << 2)];
                a += yk[v * 4 + 0] * w.x + yk[v * 4 + 1] * w.y
                   + yk[v * 4 + 2] * w.z + yk[v * 4 + 3] * w.w;
            }
            acc[c] = a;
        }
#pragma unroll
        for (int c = 0; c < 17; ++c) {
            acc[c] += __shfl_xor(acc[c], 1, 16);
            acc[c] += __shfl_xor(acc[c], 2, 16);
            acc[c] += __shfl_xor(acc[c], 4, 16);
            acc[c] += __shfl_xor(acc[c], 8, 16);
        }
        if (valid) {
            if (ksub < 16) h2[(size_t)n * 17 + ksub] = acc[ksub];
            if (ksub == 0) h2[(size_t)n * 17 + 16] = acc[16];
            if (ksub == 1) {
                float s = 0.f;
#pragma unroll
                for (int c = 0; c < 17; ++c) s += acc[c] * a2s[c];
                asrc[n] = s;
            }
            if (ksub == 2) {
                float d = 0.f;
#pragma unroll
                for (int c = 0; c < 17; ++c) d += acc[c] * a2s[17 + c];
                adst[n] = d;
            }
        }
    }
}

// softmax layer2 (2-pass online; stores UNNORMALIZED alpha and 1/denom)
__global__ __launch_bounds__(256) void k_sm2(
    const int* __restrict__ rs, const int* __restrict__ csr_src,
    const float* __restrict__ asrc, const float* __restrict__ adst,
    float* __restrict__ alpha, float* __restrict__ invden, int N)
{
    int node = blockIdx.x * 4 + (threadIdx.x >> 6);
    if (node >= N) return;
    int lane = threadIdx.x & 63;
    int base = rs[node], deg = rs[node + 1] - base;
    float ad = adst[node];
    float m = -1e30f, s = 0.f;
    for (int j = lane; j < deg; j += 64) {
        float el = asrc[csr_src[base + j]] + ad;
        el = el >= 0.f ? el : NEG_SLOPE * el;
        if (el > m) { s = s * __expf(m - el) + 1.f; m = el; }
        else        { s += __expf(el - m); }
    }
#pragma unroll
    for (int off = 1; off < 64; off <<= 1) {
        float m2 = __shfl_xor(m, off, 64);
        float s2 = __shfl_xor(s, off, 64);
        float M = fmaxf(m, m2);
        s = s * __expf(m - M) + s2 * __expf(m2 - M);
        m = M;
    }
    if (lane == 0) invden[node] = 1.f / (s + 1e-16f);
    for (int j = lane; j < deg; j += 64) {
        float el = asrc[csr_src[base + j]] + ad;
        el = el >= 0.f ? el : NEG_SLOPE * el;
        alpha[base + j] = __expf(el - m);
    }
}

// aggregate layer2 + invden + bias + log_softmax
__global__ __launch_bounds__(256) void k_out(
    const int* __restrict__ rs, const int* __restrict__ csr_src,
    const float* __restrict__ alpha, const float* __restrict__ invden,
    const float* __restrict__ h2,
    const float* __restrict__ b2, float* __restrict__ out, int N)
{
    int node = blockIdx.x * 4 + (threadIdx.x >> 6);
    if (node >= N) return;
    int lane = threadIdx.x & 63;
    int c = lane & 31, jsub = lane >> 5;
    int base = rs[node], end = rs[node + 1];
    float acc = 0.f;
    if (c < 17) {
        for (int p = base + jsub; p < end; p += 2) {
            int s = csr_src[p];
            acc += alpha[p] * h2[(size_t)s * 17 + c];
        }
    }
    acc += __shfl_xor(acc, 32, 64);  // combine the two edge halves
    acc *= invden[node];
    float logit = (c < 17) ? acc + b2[c] : -1e30f;
    float m = logit;
#pragma unroll
    for (int off = 1; off < 32; off <<= 1) m = fmaxf(m, __shfl_xor(m, off, 32));
    float p = (c < 17) ? __expf(logit - m) : 0.f;
    float ssum = p;
#pragma unroll
    for (int off = 1; off < 32; off <<= 1) ssum += __shfl_xor(ssum, off, 32);
    if (c < 17 && jsub == 0) out[(size_t)node * 17 + c] = logit - m - logf(ssum);
}

extern "C" void kernel_launch(void* const* d_in, const int* in_sizes, int n_in,
                              void* d_out, int out_size, void* d_ws, size_t ws_size,
                              hipStream_t stream)
{
    const float* x      = (const float*)d_in[0];
    const int*   ei     = (const int*)d_in[1];
    const float* W1     = (const float*)d_in[2];
    const float* asrc1w = (const float*)d_in[3];
    const float* adst1w = (const float*)d_in[4];
    const float* b1     = (const float*)d_in[5];
    const float* W2     = (const float*)d_in[6];
    const float* asrc2w = (const float*)d_in[7];
    const float* adst2w = (const float*)d_in[8];
    const float* b2     = (const float*)d_in[9];
    float* out = (float*)d_out;

    const int N = in_sizes[0] / 64;
    const int E = in_sizes[1] / 2;
    const int Etot = N + E;

    // workspace layout
    float* ws = (float*)d_ws;
    size_t o = 0;
    bf16*  y      = (bf16*)(ws + o); o += (size_t)N * 256;   // N*512 bf16
    float* wboth  = ws + o; o += 1024;
    float* asrc1  = ws + o; o += (size_t)N * 8;
    float* adst1  = ws + o; o += (size_t)N * 8;
    float* aE1    = ws + o; o += (size_t)Etot * 8;
    float* ivd1   = ws + o; o += (size_t)N * 8;
    float* h2     = ws + o; o += (size_t)N * 17;
    float* asrc2  = ws + o; o += (size_t)N;
    float* adst2  = ws + o; o += (size_t)N;
    float* aE2    = ws + o; o += (size_t)Etot;
    float* ivd2   = ws + o; o += (size_t)N;
    int* deg      = (int*)(ws + o); o += (size_t)N;
    int* cur      = (int*)(ws + o); o += (size_t)N;
    int* rs       = (int*)(ws + o); o += (size_t)N + 1;
    int* csr_src  = (int*)(ws + o); o += (size_t)Etot;

    hipMemsetAsync(deg, 0, (size_t)N * 4, stream);
    hipMemsetAsync(cur, 0, (size_t)N * 4, stream);

    // CSR build
    {
        int blk = 256, g = (Etot + blk - 1) / blk;
        k_hist<<<g, blk, 0, stream>>>(ei, E, Etot, deg);
        k_scan<<<1, 1024, 0, stream>>>(deg, rs, N);
        k_fill<<<g, blk, 0, stream>>>(ei, E, Etot, rs, cur, csr_src);
    }

    // layer 1
    k_prew<<<1, 512, 0, stream>>>(W1, asrc1w, adst1w, wboth);
    k_alpha1n<<<(N + 15) / 16, 256, 0, stream>>>(x, wboth, asrc1, adst1, N);
    k_sm1<<<(N + 3) / 4, 256, 0, stream>>>(rs, csr_src, asrc1, adst1, aE1, ivd1, N);
    k_agg_gemm1<<<(N + NPB - 1) / NPB, 512, 0, stream>>>(rs, csr_src, aE1, ivd1, x, W1, b1, y, N);

    // layer 2
    k_gemm2<<<(N + 63) / 64, 512, 0, stream>>>(y, W2, asrc2w, adst2w, h2, asrc2, adst2, N);
    k_sm2<<<(N + 3) / 4, 256, 0, stream>>>(rs, csr_src, asrc2, adst2, aE2, ivd2, N);
    k_out<<<(N + 3) / 4, 256, 0, stream>>>(rs, csr_src, aE2, ivd2, h2, b2, out, N);
}

// Round 10
// 412.999 us; speedup vs baseline: 4.1416x; 1.1050x over previous
//
#include <hip/hip_runtime.h>
#include <hip/hip_bf16.h>
#include <math.h>

#define NEG_SLOPE 0.2f
typedef __hip_bfloat16 bf16;
typedef __attribute__((ext_vector_type(8))) unsigned short ushort8;

// XOR swizzle: logical float-column c -> physical column (breaks stride-32 conflicts)
#define SWZ(c) ((c) ^ ((((c) >> 5) & 7) << 2))

__device__ __forceinline__ float bf2f(unsigned short u) {
    return __uint_as_float(((unsigned)u) << 16);
}

__device__ __forceinline__ void edge_sd(const int* __restrict__ ei, int E, int e, int& s, int& d) {
    if (e < E) { s = ei[e]; d = ei[E + e]; }
    else { s = e - E; d = s; }  // self-loop
}

// ================= CSR build =================
__global__ void k_hist(const int* __restrict__ ei, int E, int Etot, int* __restrict__ deg)
{
    int e = blockIdx.x * blockDim.x + threadIdx.x;
    if (e >= Etot) return;
    int s, d; edge_sd(ei, E, e, s, d);
    atomicAdd(&deg[d], 1);
}

__global__ __launch_bounds__(1024) void k_scan(const int* __restrict__ deg,
                                               int* __restrict__ rs, int N)
{
    __shared__ int part[1024];
    int t = threadIdx.x;
    int chunk = (N + 1023) >> 10;
    int b = t * chunk, e = min(b + chunk, N);
    int s = 0;
    for (int i = b; i < e; ++i) s += deg[i];
    part[t] = s;
    __syncthreads();
    for (int off = 1; off < 1024; off <<= 1) {
        int v = (t >= off) ? part[t - off] : 0;
        __syncthreads();
        part[t] += v;
        __syncthreads();
    }
    int excl = (t == 0) ? 0 : part[t - 1];
    for (int i = b; i < e; ++i) { rs[i] = excl; excl += deg[i]; }
    if (t == 1023) rs[N] = part[1023];
}

__global__ void k_fill(const int* __restrict__ ei, int E, int Etot,
                       const int* __restrict__ rs, int* __restrict__ cur,
                       int* __restrict__ csr_src)
{
    int e = blockIdx.x * blockDim.x + threadIdx.x;
    if (e >= Etot) return;
    int s, d; edge_sd(ei, E, e, s, d);
    int pos = rs[d] + atomicAdd(&cur[d], 1);
    csr_src[pos] = s;
}

// ================= Layer 1 =================
// wboth[k][c16]: c<8 -> src-fold head c ; c>=8 -> dst-fold head c-8
__global__ __launch_bounds__(512) void k_prew(
    const float* __restrict__ W1, const float* __restrict__ a_src,
    const float* __restrict__ a_dst, float* __restrict__ wboth)
{
    int t = threadIdx.x;           // 512 = 64 k x 8 h
    int k = t >> 3, h = t & 7;
    float s = 0.f, d = 0.f;
    const float* wr = W1 + k * 512 + h * 64;
    const float* as = a_src + h * 64;
    const float* ad = a_dst + h * 64;
#pragma unroll
    for (int c = 0; c < 64; ++c) { s += wr[c] * as[c]; d += wr[c] * ad[c]; }
    wboth[k * 16 + h] = s;
    wboth[k * 16 + 8 + h] = d;
}

// per-node attention terms: 256 thr = 4 waves x 4 nodes x 16 lanes
__global__ __launch_bounds__(256) void k_alpha1n(
    const float* __restrict__ x, const float* __restrict__ wboth,
    float* __restrict__ asrc, float* __restrict__ adst, int N)
{
    __shared__ float wl[16][64];   // transposed: wl[c][k]
    int t = threadIdx.x;
    for (int i = t; i < 1024; i += 256) {
        int k = i >> 4, c = i & 15;
        wl[c][k] = wboth[i];
    }
    __syncthreads();
    int wave = t >> 6, lane = t & 63;
    int nsub = lane >> 4, ksub = lane & 15;
    int n = blockIdx.x * 16 + wave * 4 + nsub;
    bool valid = (n < N);
    float xv[4];
#pragma unroll
    for (int i = 0; i < 4; ++i)
        xv[i] = valid ? x[(size_t)n * 64 + i * 16 + ksub] : 0.f;
    float acc[16];
#pragma unroll
    for (int c = 0; c < 16; ++c) acc[c] = 0.f;
#pragma unroll
    for (int i = 0; i < 4; ++i) {
        float xi = xv[i];
        int k = i * 16 + ksub;
#pragma unroll
        for (int c = 0; c < 16; ++c) acc[c] += xi * wl[c][k];
    }
#pragma unroll
    for (int c = 0; c < 16; ++c) {
        acc[c] += __shfl_xor(acc[c], 1, 16);
        acc[c] += __shfl_xor(acc[c], 2, 16);
        acc[c] += __shfl_xor(acc[c], 4, 16);
        acc[c] += __shfl_xor(acc[c], 8, 16);
    }
    if (valid) {
        if (ksub < 8) asrc[n * 8 + ksub] = acc[ksub];
        else          adst[n * 8 + (ksub - 8)] = acc[ksub];
    }
}

// softmax layer1: online (m,s) pass + NORMALIZED write pass.
// wave per node; lane = (j0 = lane>>3, head h = lane&7)
__global__ __launch_bounds__(256) void k_sm1(
    const int* __restrict__ rs, const int* __restrict__ csr_src,
    const float* __restrict__ asrc, const float* __restrict__ adst,
    float* __restrict__ aE, int N)
{
    int node = blockIdx.x * 4 + (threadIdx.x >> 6);
    if (node >= N) return;
    int lane = threadIdx.x & 63;
    int h = lane & 7, j0 = lane >> 3;
    int base = rs[node], deg = rs[node + 1] - base;
    float ad = adst[node * 8 + h];
    float m = -1e30f, s = 0.f;
    for (int j = j0; j < deg; j += 8) {
        int src = csr_src[base + j];
        float el = asrc[src * 8 + h] + ad;
        el = el >= 0.f ? el : NEG_SLOPE * el;
        if (el > m) { s = s * __expf(m - el) + 1.f; m = el; }
        else        { s += __expf(el - m); }
    }
#pragma unroll
    for (int off = 8; off < 64; off <<= 1) {
        float m2 = __shfl_xor(m, off, 64);
        float s2 = __shfl_xor(s, off, 64);
        float M = fmaxf(m, m2);
        s = s * __expf(m - M) + s2 * __expf(m2 - M);
        m = M;
    }
    float inv = 1.f / (s + 1e-16f);
    for (int j = j0; j < deg; j += 8) {
        int src = csr_src[base + j];
        float el = asrc[src * 8 + h] + ad;
        el = el >= 0.f ? el : NEG_SLOPE * el;
        aE[(size_t)(base + j) * 8 + h] = __expf(el - m) * inv;
    }
}

// ===== fused: x-space aggregate (wave per node) + per-head GEMM + bias + ELU =====
// R7-PROVEN FORM (142 us, 32 VGPR, 79% occ) — do not restructure:
//   pad-9 zs layout, scalar b32 broadcast phase-2 reads, coalesced W1 rows.
//   (float4 phase-2 reads spill: R5, R8. zs-transpose+invden tail: R9, +35 us.)
#define NPB 8
__global__ __launch_bounds__(512) void k_agg_gemm1(
    const int* __restrict__ rs, const int* __restrict__ csr_src,
    const float* __restrict__ aE, const float* __restrict__ x,
    const float* __restrict__ W1, const float* __restrict__ b1,
    bf16* __restrict__ y, int N)
{
    __shared__ float zs[NPB][64 * 9];   // 18 KB
    int t = threadIdx.x;
    int wave = t >> 6, lane = t & 63;
    int n = blockIdx.x * NPB + wave;

    if (n < N) {
        int base = rs[n], deg = rs[n + 1] - base;
        float acc[8];
#pragma unroll
        for (int h = 0; h < 8; ++h) acc[h] = 0.f;
        for (int j0 = 0; j0 < deg; j0 += 64) {
            int cnt = min(64, deg - j0);
            int sidx = csr_src[base + j0 + min(lane, cnt - 1)];
#pragma unroll 2
            for (int j = 0; j < cnt; ++j) {
                int s = __shfl(sidx, j, 64);
                float xv = x[(size_t)s * 64 + lane];
                const float4* ap = (const float4*)(aE + (size_t)(base + j0 + j) * 8);
                float4 a0 = ap[0], a1 = ap[1];
                acc[0] += a0.x * xv; acc[1] += a0.y * xv;
                acc[2] += a0.z * xv; acc[3] += a0.w * xv;
                acc[4] += a1.x * xv; acc[5] += a1.y * xv;
                acc[6] += a1.z * xv; acc[7] += a1.w * xv;
            }
        }
#pragma unroll
        for (int h = 0; h < 8; ++h) zs[wave][lane * 9 + h] = acc[h];
    } else {
#pragma unroll
        for (int h = 0; h < 8; ++h) zs[wave][lane * 9 + h] = 0.f;
    }
    __syncthreads();

    // phase 2: y[n, t] = elu( sum_k zs[m][k*9 + (t>>6)] * W1[k*512 + t] + b1[t] )
    int n0 = blockIdx.x * NPB;
    int h = t >> 6;
    float acc2[NPB];
#pragma unroll
    for (int m = 0; m < NPB; ++m) acc2[m] = 0.f;
#pragma unroll 8
    for (int k = 0; k < 64; ++k) {
        float w = W1[k * 512 + t];
#pragma unroll
        for (int m = 0; m < NPB; ++m) acc2[m] += zs[m][k * 9 + h] * w;
    }
    float bias = b1[t];
#pragma unroll
    for (int m = 0; m < NPB; ++m) {
        int nn = n0 + m;
        if (nn < N) {
            float v = acc2[m] + bias;
            v = v > 0.f ? v : __expf(v) - 1.f;
            y[(size_t)nn * 512 + t] = __float2bfloat16(v);
        }
    }
}

// ================= Layer 2 =================
// h2 = y @ W2 (+ fused attention dots). 512 thr = 8 waves x 4 nodes x 16 lanes.
// 64 nodes per block (2 passes) to amortize W2 staging; W2t XOR-swizzled.
__global__ __launch_bounds__(512) void k_gemm2(
    const bf16* __restrict__ y, const float* __restrict__ W2,
    const float* __restrict__ a_src2, const float* __restrict__ a_dst2,
    float* __restrict__ h2, float* __restrict__ asrc, float* __restrict__ adst, int N)
{
    __shared__ float W2t[17][512];
    __shared__ float a2s[34];
    int t = threadIdx.x;
    for (int i = t; i < 17 * 512; i += 512) {
        int c = i >> 9, k = i & 511;
        W2t[c][SWZ(k)] = W2[k * 17 + c];
    }
    if (t < 17) a2s[t] = a_src2[t];
    else if (t < 34) a2s[t] = a_dst2[t - 17];
    __syncthreads();

    int wave = t >> 6, lane = t & 63;
    int nsub = lane >> 4, ksub = lane & 15;
    int kx = ksub & 7;

#pragma unroll
    for (int pass = 0; pass < 2; ++pass) {
        int n = blockIdx.x * 64 + pass * 32 + wave * 4 + nsub;
        bool valid = (n < N);

        float yk[32];
        if (valid) {
            const ushort8* yr = (const ushort8*)(y + (size_t)n * 512 + ksub * 32);
#pragma unroll
            for (int v = 0; v < 4; ++v) {
                ushort8 u = yr[v];
#pragma unroll
                for (int j = 0; j < 8; ++j) yk[v * 8 + j] = bf2f(u[j]);
            }
        } else {
#pragma unroll
            for (int i = 0; i < 32; ++i) yk[i] = 0.f;
        }

        float acc[17];
#pragma unroll
        for (int c = 0; c < 17; ++c) {
            float a = 0.f;
#pragma unroll
            for (int v = 0; v < 8; ++v) {
                // physical chunk (v ^ kx) holds logical k-chunk v
                const float4 w = *(const float4*)&W2t[c][ksub * 32 + ((v ^ kx) << 2)];
                a += yk[v * 4 + 0] * w.x + yk[v * 4 + 1] * w.y
                   + yk[v * 4 + 2] * w.z + yk[v * 4 + 3] * w.w;
            }
            acc[c] = a;
        }
#pragma unroll
        for (int c = 0; c < 17; ++c) {
            acc[c] += __shfl_xor(acc[c], 1, 16);
            acc[c] += __shfl_xor(acc[c], 2, 16);
            acc[c] += __shfl_xor(acc[c], 4, 16);
            acc[c] += __shfl_xor(acc[c], 8, 16);
        }
        if (valid) {
            if (ksub < 16) h2[(size_t)n * 17 + ksub] = acc[ksub];
            if (ksub == 0) h2[(size_t)n * 17 + 16] = acc[16];
            if (ksub == 1) {
                float s = 0.f;
#pragma unroll
                for (int c = 0; c < 17; ++c) s += acc[c] * a2s[c];
                asrc[n] = s;
            }
            if (ksub == 2) {
                float d = 0.f;
#pragma unroll
                for (int c = 0; c < 17; ++c) d += acc[c] * a2s[17 + c];
                adst[n] = d;
            }
        }
    }
}

// softmax layer2: online (m,s) pass + NORMALIZED write pass. wave per node.
__global__ __launch_bounds__(256) void k_sm2(
    const int* __restrict__ rs, const int* __restrict__ csr_src,
    const float* __restrict__ asrc, const float* __restrict__ adst,
    float* __restrict__ alpha, int N)
{
    int node = blockIdx.x * 4 + (threadIdx.x >> 6);
    if (node >= N) return;
    int lane = threadIdx.x & 63;
    int base = rs[node], deg = rs[node + 1] - base;
    float ad = adst[node];
    float m = -1e30f, s = 0.f;
    for (int j = lane; j < deg; j += 64) {
        float el = asrc[csr_src[base + j]] + ad;
        el = el >= 0.f ? el : NEG_SLOPE * el;
        if (el > m) { s = s * __expf(m - el) + 1.f; m = el; }
        else        { s += __expf(el - m); }
    }
#pragma unroll
    for (int off = 1; off < 64; off <<= 1) {
        float m2 = __shfl_xor(m, off, 64);
        float s2 = __shfl_xor(s, off, 64);
        float M = fmaxf(m, m2);
        s = s * __expf(m - M) + s2 * __expf(m2 - M);
        m = M;
    }
    float inv = 1.f / (s + 1e-16f);
    for (int j = lane; j < deg; j += 64) {
        float el = asrc[csr_src[base + j]] + ad;
        el = el >= 0.f ? el : NEG_SLOPE * el;
        alpha[base + j] = __expf(el - m) * inv;
    }
}

// aggregate layer2 + bias + log_softmax: wave per node; lane = (jsub = lane>>5, c = lane&31)
__global__ __launch_bounds__(256) void k_out(
    const int* __restrict__ rs, const int* __restrict__ csr_src,
    const float* __restrict__ alpha, const float* __restrict__ h2,
    const float* __restrict__ b2, float* __restrict__ out, int N)
{
    int node = blockIdx.x * 4 + (threadIdx.x >> 6);
    if (node >= N) return;
    int lane = threadIdx.x & 63;
    int c = lane & 31, jsub = lane >> 5;
    int base = rs[node], end = rs[node + 1];
    float acc = 0.f;
    if (c < 17) {
        for (int p = base + jsub; p < end; p += 2) {
            int s = csr_src[p];
            acc += alpha[p] * h2[(size_t)s * 17 + c];
        }
    }
    acc += __shfl_xor(acc, 32, 64);  // combine the two edge halves
    float logit = (c < 17) ? acc + b2[c] : -1e30f;
    float m = logit;
#pragma unroll
    for (int off = 1; off < 32; off <<= 1) m = fmaxf(m, __shfl_xor(m, off, 32));
    float p = (c < 17) ? __expf(logit - m) : 0.f;
    float ssum = p;
#pragma unroll
    for (int off = 1; off < 32; off <<= 1) ssum += __shfl_xor(ssum, off, 32);
    if (c < 17 && jsub == 0) out[(size_t)node * 17 + c] = logit - m - logf(ssum);
}

extern "C" void kernel_launch(void* const* d_in, const int* in_sizes, int n_in,
                              void* d_out, int out_size, void* d_ws, size_t ws_size,
                              hipStream_t stream)
{
    const float* x      = (const float*)d_in[0];
    const int*   ei     = (const int*)d_in[1];
    const float* W1     = (const float*)d_in[2];
    const float* asrc1w = (const float*)d_in[3];
    const float* adst1w = (const float*)d_in[4];
    const float* b1     = (const float*)d_in[5];
    const float* W2     = (const float*)d_in[6];
    const float* asrc2w = (const float*)d_in[7];
    const float* adst2w = (const float*)d_in[8];
    const float* b2     = (const float*)d_in[9];
    float* out = (float*)d_out;

    const int N = in_sizes[0] / 64;
    const int E = in_sizes[1] / 2;
    const int Etot = N + E;

    // workspace layout
    float* ws = (float*)d_ws;
    size_t o = 0;
    bf16*  y      = (bf16*)(ws + o); o += (size_t)N * 256;   // N*512 bf16
    float* wboth  = ws + o; o += 1024;
    float* asrc1  = ws + o; o += (size_t)N * 8;
    float* adst1  = ws + o; o += (size_t)N * 8;
    float* aE1    = ws + o; o += (size_t)Etot * 8;
    float* h2     = ws + o; o += (size_t)N * 17;
    float* asrc2  = ws + o; o += (size_t)N;
    float* adst2  = ws + o; o += (size_t)N;
    float* aE2    = ws + o; o += (size_t)Etot;
    int* deg      = (int*)(ws + o); o += (size_t)N;
    int* cur      = (int*)(ws + o); o += (size_t)N;
    int* rs       = (int*)(ws + o); o += (size_t)N + 1;
    int* csr_src  = (int*)(ws + o); o += (size_t)Etot;

    hipMemsetAsync(deg, 0, (size_t)N * 4, stream);
    hipMemsetAsync(cur, 0, (size_t)N * 4, stream);

    // CSR build
    {
        int blk = 256, g = (Etot + blk - 1) / blk;
        k_hist<<<g, blk, 0, stream>>>(ei, E, Etot, deg);
        k_scan<<<1, 1024, 0, stream>>>(deg, rs, N);
        k_fill<<<g, blk, 0, stream>>>(ei, E, Etot, rs, cur, csr_src);
    }

    // layer 1
    k_prew<<<1, 512, 0, stream>>>(W1, asrc1w, adst1w, wboth);
    k_alpha1n<<<(N + 15) / 16, 256, 0, stream>>>(x, wboth, asrc1, adst1, N);
    k_sm1<<<(N + 3) / 4, 256, 0, stream>>>(rs, csr_src, asrc1, adst1, aE1, N);
    k_agg_gemm1<<<(N + NPB - 1) / NPB, 512, 0, stream>>>(rs, csr_src, aE1, x, W1, b1, y, N);

    // layer 2
    k_gemm2<<<(N + 63) / 64, 512, 0, stream>>>(y, W2, asrc2w, adst2w, h2, asrc2, adst2, N);
    k_sm2<<<(N + 3) / 4, 256, 0, stream>>>(rs, csr_src, asrc2, adst2, aE2, N);
    k_out<<<(N + 3) / 4, 256, 0, stream>>>(rs, csr_src, aE2, h2, b2, out, N);
}

// Round 11
// 397.601 us; speedup vs baseline: 4.3020x; 1.0387x over previous
//
#include <hip/hip_runtime.h>
#include <hip/hip_bf16.h>
#include <math.h>

#define NEG_SLOPE 0.2f
typedef __hip_bfloat16 bf16;
typedef __attribute__((ext_vector_type(8))) unsigned short ushort8;

// XOR swizzle: logical float-column c -> physical column (breaks stride-32 conflicts)
#define SWZ(c) ((c) ^ ((((c) >> 5) & 7) << 2))

__device__ __forceinline__ float bf2f(unsigned short u) {
    return __uint_as_float(((unsigned)u) << 16);
}

__device__ __forceinline__ void edge_sd(const int* __restrict__ ei, int E, int e, int& s, int& d) {
    if (e < E) { s = ei[e]; d = ei[E + e]; }
    else { s = e - E; d = s; }  // self-loop
}

// ================= CSR build =================
__global__ void k_hist(const int* __restrict__ ei, int E, int Etot, int* __restrict__ deg)
{
    int e = blockIdx.x * blockDim.x + threadIdx.x;
    if (e >= Etot) return;
    int s, d; edge_sd(ei, E, e, s, d);
    atomicAdd(&deg[d], 1);
}

__global__ __launch_bounds__(1024) void k_scan(const int* __restrict__ deg,
                                               int* __restrict__ rs, int N)
{
    __shared__ int part[1024];
    int t = threadIdx.x;
    int chunk = (N + 1023) >> 10;
    int b = t * chunk, e = min(b + chunk, N);
    int s = 0;
    for (int i = b; i < e; ++i) s += deg[i];
    part[t] = s;
    __syncthreads();
    for (int off = 1; off < 1024; off <<= 1) {
        int v = (t >= off) ? part[t - off] : 0;
        __syncthreads();
        part[t] += v;
        __syncthreads();
    }
    int excl = (t == 0) ? 0 : part[t - 1];
    for (int i = b; i < e; ++i) { rs[i] = excl; excl += deg[i]; }
    if (t == 1023) rs[N] = part[1023];
}

__global__ void k_fill(const int* __restrict__ ei, int E, int Etot,
                       const int* __restrict__ rs, int* __restrict__ cur,
                       int* __restrict__ csr_src)
{
    int e = blockIdx.x * blockDim.x + threadIdx.x;
    if (e >= Etot) return;
    int s, d; edge_sd(ei, E, e, s, d);
    int pos = rs[d] + atomicAdd(&cur[d], 1);
    csr_src[pos] = s;
}

// ================= Layer 1 =================
// wboth[k][c16]: c<8 -> src-fold head c ; c>=8 -> dst-fold head c-8
__global__ __launch_bounds__(512) void k_prew(
    const float* __restrict__ W1, const float* __restrict__ a_src,
    const float* __restrict__ a_dst, float* __restrict__ wboth)
{
    int t = threadIdx.x;           // 512 = 64 k x 8 h
    int k = t >> 3, h = t & 7;
    float s = 0.f, d = 0.f;
    const float* wr = W1 + k * 512 + h * 64;
    const float* as = a_src + h * 64;
    const float* ad = a_dst + h * 64;
#pragma unroll
    for (int c = 0; c < 64; ++c) { s += wr[c] * as[c]; d += wr[c] * ad[c]; }
    wboth[k * 16 + h] = s;
    wboth[k * 16 + 8 + h] = d;
}

// per-node attention terms: 256 thr = 4 waves x 4 nodes x 16 lanes
__global__ __launch_bounds__(256) void k_alpha1n(
    const float* __restrict__ x, const float* __restrict__ wboth,
    float* __restrict__ asrc, float* __restrict__ adst, int N)
{
    __shared__ float wl[16][64];   // transposed: wl[c][k]
    int t = threadIdx.x;
    for (int i = t; i < 1024; i += 256) {
        int k = i >> 4, c = i & 15;
        wl[c][k] = wboth[i];
    }
    __syncthreads();
    int wave = t >> 6, lane = t & 63;
    int nsub = lane >> 4, ksub = lane & 15;
    int n = blockIdx.x * 16 + wave * 4 + nsub;
    bool valid = (n < N);
    float xv[4];
#pragma unroll
    for (int i = 0; i < 4; ++i)
        xv[i] = valid ? x[(size_t)n * 64 + i * 16 + ksub] : 0.f;
    float acc[16];
#pragma unroll
    for (int c = 0; c < 16; ++c) acc[c] = 0.f;
#pragma unroll
    for (int i = 0; i < 4; ++i) {
        float xi = xv[i];
        int k = i * 16 + ksub;
#pragma unroll
        for (int c = 0; c < 16; ++c) acc[c] += xi * wl[c][k];
    }
#pragma unroll
    for (int c = 0; c < 16; ++c) {
        acc[c] += __shfl_xor(acc[c], 1, 16);
        acc[c] += __shfl_xor(acc[c], 2, 16);
        acc[c] += __shfl_xor(acc[c], 4, 16);
        acc[c] += __shfl_xor(acc[c], 8, 16);
    }
    if (valid) {
        if (ksub < 8) asrc[n * 8 + ksub] = acc[ksub];
        else          adst[n * 8 + (ksub - 8)] = acc[ksub];
    }
}

// softmax layer1: online (m,s) pass + NORMALIZED write pass.
// wave per node; lane = (j0 = lane>>3, head h = lane&7)
__global__ __launch_bounds__(256) void k_sm1(
    const int* __restrict__ rs, const int* __restrict__ csr_src,
    const float* __restrict__ asrc, const float* __restrict__ adst,
    float* __restrict__ aE, int N)
{
    int node = blockIdx.x * 4 + (threadIdx.x >> 6);
    if (node >= N) return;
    int lane = threadIdx.x & 63;
    int h = lane & 7, j0 = lane >> 3;
    int base = rs[node], deg = rs[node + 1] - base;
    float ad = adst[node * 8 + h];
    float m = -1e30f, s = 0.f;
    for (int j = j0; j < deg; j += 8) {
        int src = csr_src[base + j];
        float el = asrc[src * 8 + h] + ad;
        el = el >= 0.f ? el : NEG_SLOPE * el;
        if (el > m) { s = s * __expf(m - el) + 1.f; m = el; }
        else        { s += __expf(el - m); }
    }
#pragma unroll
    for (int off = 8; off < 64; off <<= 1) {
        float m2 = __shfl_xor(m, off, 64);
        float s2 = __shfl_xor(s, off, 64);
        float M = fmaxf(m, m2);
        s = s * __expf(m - M) + s2 * __expf(m2 - M);
        m = M;
    }
    float inv = 1.f / (s + 1e-16f);
    for (int j = j0; j < deg; j += 8) {
        int src = csr_src[base + j];
        float el = asrc[src * 8 + h] + ad;
        el = el >= 0.f ? el : NEG_SLOPE * el;
        aE[(size_t)(base + j) * 8 + h] = __expf(el - m) * inv;
    }
}

// ===== fused: x-space aggregate (wave per node) + per-head GEMM + bias + ELU =====
// phase 1: wave m = node n0+m; lane = k; acc[8] = all heads.
//   zs[wave][h*64+lane] write: consecutive lanes -> conflict-free (R9-proven).
// phase 2: b128 broadcast zs reads, k4 loop NOT unrolled (#pragma unroll 1)
//   — R8's spill was caused by FULL unroll (16x12 live values); unroll 1 keeps
//   the live set at ~20 regs. If WRITE_SIZE explodes again -> permanent revert.
#define NPB 8
__global__ __launch_bounds__(512) void k_agg_gemm1(
    const int* __restrict__ rs, const int* __restrict__ csr_src,
    const float* __restrict__ aE, const float* __restrict__ x,
    const float* __restrict__ W1, const float* __restrict__ b1,
    bf16* __restrict__ y, int N)
{
    __shared__ float zs[NPB][512];   // 16 KB
    int t = threadIdx.x;
    int wave = t >> 6, lane = t & 63;
    int n = blockIdx.x * NPB + wave;

    if (n < N) {
        int base = rs[n], deg = rs[n + 1] - base;
        float acc[8];
#pragma unroll
        for (int h = 0; h < 8; ++h) acc[h] = 0.f;
        for (int j0 = 0; j0 < deg; j0 += 64) {
            int cnt = min(64, deg - j0);
            int sidx = csr_src[base + j0 + min(lane, cnt - 1)];
#pragma unroll 2
            for (int j = 0; j < cnt; ++j) {
                int s = __shfl(sidx, j, 64);
                float xv = x[(size_t)s * 64 + lane];
                const float4* ap = (const float4*)(aE + (size_t)(base + j0 + j) * 8);
                float4 a0 = ap[0], a1 = ap[1];
                acc[0] += a0.x * xv; acc[1] += a0.y * xv;
                acc[2] += a0.z * xv; acc[3] += a0.w * xv;
                acc[4] += a1.x * xv; acc[5] += a1.y * xv;
                acc[6] += a1.z * xv; acc[7] += a1.w * xv;
            }
        }
#pragma unroll
        for (int h = 0; h < 8; ++h) zs[wave][h * 64 + lane] = acc[h];
    } else {
#pragma unroll
        for (int h = 0; h < 8; ++h) zs[wave][h * 64 + lane] = 0.f;
    }
    __syncthreads();

    // phase 2: y[n0+m][t] = elu( sum_k zs[m][h*64+k] * W1[k*512+t] + b1[t] ), h = t>>6
    int n0 = blockIdx.x * NPB;
    int h = t >> 6;
    float acc2[NPB];
#pragma unroll
    for (int m = 0; m < NPB; ++m) acc2[m] = 0.f;
#pragma unroll 1
    for (int k4 = 0; k4 < 16; ++k4) {
        int k = k4 * 4;
        float w0 = W1[(k + 0) * 512 + t];
        float w1 = W1[(k + 1) * 512 + t];
        float w2 = W1[(k + 2) * 512 + t];
        float w3 = W1[(k + 3) * 512 + t];
#pragma unroll
        for (int m = 0; m < NPB; ++m) {
            float4 zv = *(const float4*)&zs[m][h * 64 + k];
            acc2[m] += zv.x * w0 + zv.y * w1 + zv.z * w2 + zv.w * w3;
        }
    }
    float bias = b1[t];
#pragma unroll
    for (int m = 0; m < NPB; ++m) {
        int nn = n0 + m;
        if (nn < N) {
            float v = acc2[m] + bias;
            v = v > 0.f ? v : __expf(v) - 1.f;
            y[(size_t)nn * 512 + t] = __float2bfloat16(v);
        }
    }
}

// ================= Layer 2 =================
// h2 = y @ W2 (+ fused attention dots). 512 thr = 8 waves x 4 nodes x 16 lanes.
// 64 nodes per block (2 passes) to amortize W2 staging; W2t XOR-swizzled.
__global__ __launch_bounds__(512) void k_gemm2(
    const bf16* __restrict__ y, const float* __restrict__ W2,
    const float* __restrict__ a_src2, const float* __restrict__ a_dst2,
    float* __restrict__ h2, float* __restrict__ asrc, float* __restrict__ adst, int N)
{
    __shared__ float W2t[17][512];
    __shared__ float a2s[34];
    int t = threadIdx.x;
    for (int i = t; i < 17 * 512; i += 512) {
        int c = i >> 9, k = i & 511;
        W2t[c][SWZ(k)] = W2[k * 17 + c];
    }
    if (t < 17) a2s[t] = a_src2[t];
    else if (t < 34) a2s[t] = a_dst2[t - 17];
    __syncthreads();

    int wave = t >> 6, lane = t & 63;
    int nsub = lane >> 4, ksub = lane & 15;
    int kx = ksub & 7;

#pragma unroll
    for (int pass = 0; pass < 2; ++pass) {
        int n = blockIdx.x * 64 + pass * 32 + wave * 4 + nsub;
        bool valid = (n < N);

        float yk[32];
        if (valid) {
            const ushort8* yr = (const ushort8*)(y + (size_t)n * 512 + ksub * 32);
#pragma unroll
            for (int v = 0; v < 4; ++v) {
                ushort8 u = yr[v];
#pragma unroll
                for (int j = 0; j < 8; ++j) yk[v * 8 + j] = bf2f(u[j]);
            }
        } else {
#pragma unroll
            for (int i = 0; i < 32; ++i) yk[i] = 0.f;
        }

        float acc[17];
#pragma unroll
        for (int c = 0; c < 17; ++c) {
            float a = 0.f;
#pragma unroll
            for (int v = 0; v < 8; ++v) {
                // physical chunk (v ^ kx) holds logical k-chunk v
                const float4 w = *(const float4*)&W2t[c][ksub * 32 + ((v ^ kx) << 2)];
                a += yk[v * 4 + 0] * w.x + yk[v * 4 + 1] * w.y
                   + yk[v * 4 + 2] * w.z + yk[v * 4 + 3] * w.w;
            }
            acc[c] = a;
        }
#pragma unroll
        for (int c = 0; c < 17; ++c) {
            acc[c] += __shfl_xor(acc[c], 1, 16);
            acc[c] += __shfl_xor(acc[c], 2, 16);
            acc[c] += __shfl_xor(acc[c], 4, 16);
            acc[c] += __shfl_xor(acc[c], 8, 16);
        }
        if (valid) {
            if (ksub < 16) h2[(size_t)n * 17 + ksub] = acc[ksub];
            if (ksub == 0) h2[(size_t)n * 17 + 16] = acc[16];
            if (ksub == 1) {
                float s = 0.f;
#pragma unroll
                for (int c = 0; c < 17; ++c) s += acc[c] * a2s[c];
                asrc[n] = s;
            }
            if (ksub == 2) {
                float d = 0.f;
#pragma unroll
                for (int c = 0; c < 17; ++c) d += acc[c] * a2s[17 + c];
                adst[n] = d;
            }
        }
    }
}

// ===== fused layer2 softmax + aggregate + bias + log_softmax =====
// wave per node. pass A: all 64 lanes online (m,s) over edges.
// pass B: lane = (jsub = lane>>5, c = lane&31); alpha recomputed inline.
__global__ __launch_bounds__(256) void k_out(
    const int* __restrict__ rs, const int* __restrict__ csr_src,
    const float* __restrict__ asrc, const float* __restrict__ adst,
    const float* __restrict__ h2,
    const float* __restrict__ b2, float* __restrict__ out, int N)
{
    int node = blockIdx.x * 4 + (threadIdx.x >> 6);
    if (node >= N) return;
    int lane = threadIdx.x & 63;
    int base = rs[node], deg = rs[node + 1] - base;
    float ad = adst[node];

    // pass A: online (m,s)
    float m = -1e30f, s = 0.f;
    for (int j = lane; j < deg; j += 64) {
        float el = asrc[csr_src[base + j]] + ad;
        el = el >= 0.f ? el : NEG_SLOPE * el;
        if (el > m) { s = s * __expf(m - el) + 1.f; m = el; }
        else        { s += __expf(el - m); }
    }
#pragma unroll
    for (int off = 1; off < 64; off <<= 1) {
        float m2 = __shfl_xor(m, off, 64);
        float s2 = __shfl_xor(s, off, 64);
        float M = fmaxf(m, m2);
        s = s * __expf(m - M) + s2 * __expf(m2 - M);
        m = M;
    }
    float inv = 1.f / (s + 1e-16f);

    // pass B: aggregate with inline alpha
    int c = lane & 31, jsub = lane >> 5;
    float acc = 0.f;
    if (c < 17) {
        for (int p = base + jsub; p < base + deg; p += 2) {
            int src = csr_src[p];
            float el = asrc[src] + ad;
            el = el >= 0.f ? el : NEG_SLOPE * el;
            float alpha = __expf(el - m) * inv;
            acc += alpha * h2[(size_t)src * 17 + c];
        }
    }
    acc += __shfl_xor(acc, 32, 64);  // combine the two edge halves
    float logit = (c < 17) ? acc + b2[c] : -1e30f;
    float mm = logit;
#pragma unroll
    for (int off = 1; off < 32; off <<= 1) mm = fmaxf(mm, __shfl_xor(mm, off, 32));
    float p = (c < 17) ? __expf(logit - mm) : 0.f;
    float ssum = p;
#pragma unroll
    for (int off = 1; off < 32; off <<= 1) ssum += __shfl_xor(ssum, off, 32);
    if (c < 17 && jsub == 0) out[(size_t)node * 17 + c] = logit - mm - logf(ssum);
}

extern "C" void kernel_launch(void* const* d_in, const int* in_sizes, int n_in,
                              void* d_out, int out_size, void* d_ws, size_t ws_size,
                              hipStream_t stream)
{
    const float* x      = (const float*)d_in[0];
    const int*   ei     = (const int*)d_in[1];
    const float* W1     = (const float*)d_in[2];
    const float* asrc1w = (const float*)d_in[3];
    const float* adst1w = (const float*)d_in[4];
    const float* b1     = (const float*)d_in[5];
    const float* W2     = (const float*)d_in[6];
    const float* asrc2w = (const float*)d_in[7];
    const float* adst2w = (const float*)d_in[8];
    const float* b2     = (const float*)d_in[9];
    float* out = (float*)d_out;

    const int N = in_sizes[0] / 64;
    const int E = in_sizes[1] / 2;
    const int Etot = N + E;

    // workspace layout
    float* ws = (float*)d_ws;
    size_t o = 0;
    bf16*  y      = (bf16*)(ws + o); o += (size_t)N * 256;   // N*512 bf16
    float* wboth  = ws + o; o += 1024;
    float* asrc1  = ws + o; o += (size_t)N * 8;
    float* adst1  = ws + o; o += (size_t)N * 8;
    float* aE1    = ws + o; o += (size_t)Etot * 8;
    float* h2     = ws + o; o += (size_t)N * 17;
    float* asrc2  = ws + o; o += (size_t)N;
    float* adst2  = ws + o; o += (size_t)N;
    int* deg      = (int*)(ws + o); o += (size_t)N;
    int* cur      = (int*)(ws + o); o += (size_t)N;
    int* rs       = (int*)(ws + o); o += (size_t)N + 1;
    int* csr_src  = (int*)(ws + o); o += (size_t)Etot;

    hipMemsetAsync(deg, 0, (size_t)N * 4, stream);
    hipMemsetAsync(cur, 0, (size_t)N * 4, stream);

    // CSR build
    {
        int blk = 256, g = (Etot + blk - 1) / blk;
        k_hist<<<g, blk, 0, stream>>>(ei, E, Etot, deg);
        k_scan<<<1, 1024, 0, stream>>>(deg, rs, N);
        k_fill<<<g, blk, 0, stream>>>(ei, E, Etot, rs, cur, csr_src);
    }

    // layer 1
    k_prew<<<1, 512, 0, stream>>>(W1, asrc1w, adst1w, wboth);
    k_alpha1n<<<(N + 15) / 16, 256, 0, stream>>>(x, wboth, asrc1, adst1, N);
    k_sm1<<<(N + 3) / 4, 256, 0, stream>>>(rs, csr_src, asrc1, adst1, aE1, N);
    k_agg_gemm1<<<(N + NPB - 1) / NPB, 512, 0, stream>>>(rs, csr_src, aE1, x, W1, b1, y, N);

    // layer 2
    k_gemm2<<<(N + 63) / 64, 512, 0, stream>>>(y, W2, asrc2w, adst2w, h2, asrc2, adst2, N);
    k_out<<<(N + 3) / 4, 256, 0, stream>>>(rs, csr_src, asrc2, adst2, h2, b2, out, N);
}

// Round 12
// 394.180 us; speedup vs baseline: 4.3393x; 1.0087x over previous
//
#include <hip/hip_runtime.h>
#include <hip/hip_bf16.h>
#include <math.h>

#define NEG_SLOPE 0.2f
typedef __hip_bfloat16 bf16;
typedef __attribute__((ext_vector_type(8))) unsigned short ushort8;

// XOR swizzle: logical float-column c -> physical column (breaks stride-32 conflicts)
#define SWZ(c) ((c) ^ ((((c) >> 5) & 7) << 2))

__device__ __forceinline__ float bf2f(unsigned short u) {
    return __uint_as_float(((unsigned)u) << 16);
}

__device__ __forceinline__ void edge_sd(const int* __restrict__ ei, int E, int e, int& s, int& d) {
    if (e < E) { s = ei[e]; d = ei[E + e]; }
    else { s = e - E; d = s; }  // self-loop
}

// ================= CSR build =================
__global__ void k_hist(const int* __restrict__ ei, int E, int Etot, int* __restrict__ deg)
{
    int e = blockIdx.x * blockDim.x + threadIdx.x;
    if (e >= Etot) return;
    int s, d; edge_sd(ei, E, e, s, d);
    atomicAdd(&deg[d], 1);
}

__global__ __launch_bounds__(1024) void k_scan(const int* __restrict__ deg,
                                               int* __restrict__ rs, int N)
{
    __shared__ int part[1024];
    int t = threadIdx.x;
    int chunk = (N + 1023) >> 10;
    int b = t * chunk, e = min(b + chunk, N);
    int s = 0;
    for (int i = b; i < e; ++i) s += deg[i];
    part[t] = s;
    __syncthreads();
    for (int off = 1; off < 1024; off <<= 1) {
        int v = (t >= off) ? part[t - off] : 0;
        __syncthreads();
        part[t] += v;
        __syncthreads();
    }
    int excl = (t == 0) ? 0 : part[t - 1];
    for (int i = b; i < e; ++i) { rs[i] = excl; excl += deg[i]; }
    if (t == 1023) rs[N] = part[1023];
}

__global__ void k_fill(const int* __restrict__ ei, int E, int Etot,
                       const int* __restrict__ rs, int* __restrict__ cur,
                       int* __restrict__ csr_src)
{
    int e = blockIdx.x * blockDim.x + threadIdx.x;
    if (e >= Etot) return;
    int s, d; edge_sd(ei, E, e, s, d);
    int pos = rs[d] + atomicAdd(&cur[d], 1);
    csr_src[pos] = s;
}

// ================= Layer 1 =================
// wboth[k][c16]: c<8 -> src-fold head c ; c>=8 -> dst-fold head c-8
__global__ __launch_bounds__(512) void k_prew(
    const float* __restrict__ W1, const float* __restrict__ a_src,
    const float* __restrict__ a_dst, float* __restrict__ wboth)
{
    int t = threadIdx.x;           // 512 = 64 k x 8 h
    int k = t >> 3, h = t & 7;
    float s = 0.f, d = 0.f;
    const float* wr = W1 + k * 512 + h * 64;
    const float* as = a_src + h * 64;
    const float* ad = a_dst + h * 64;
#pragma unroll
    for (int c = 0; c < 64; ++c) { s += wr[c] * as[c]; d += wr[c] * ad[c]; }
    wboth[k * 16 + h] = s;
    wboth[k * 16 + 8 + h] = d;
}

// per-node attention terms: 256 thr = 4 waves x 4 nodes x 16 lanes
__global__ __launch_bounds__(256) void k_alpha1n(
    const float* __restrict__ x, const float* __restrict__ wboth,
    float* __restrict__ asrc, float* __restrict__ adst, int N)
{
    __shared__ float wl[16][64];   // transposed: wl[c][k]
    int t = threadIdx.x;
    for (int i = t; i < 1024; i += 256) {
        int k = i >> 4, c = i & 15;
        wl[c][k] = wboth[i];
    }
    __syncthreads();
    int wave = t >> 6, lane = t & 63;
    int nsub = lane >> 4, ksub = lane & 15;
    int n = blockIdx.x * 16 + wave * 4 + nsub;
    bool valid = (n < N);
    float xv[4];
#pragma unroll
    for (int i = 0; i < 4; ++i)
        xv[i] = valid ? x[(size_t)n * 64 + i * 16 + ksub] : 0.f;
    float acc[16];
#pragma unroll
    for (int c = 0; c < 16; ++c) acc[c] = 0.f;
#pragma unroll
    for (int i = 0; i < 4; ++i) {
        float xi = xv[i];
        int k = i * 16 + ksub;
#pragma unroll
        for (int c = 0; c < 16; ++c) acc[c] += xi * wl[c][k];
    }
#pragma unroll
    for (int c = 0; c < 16; ++c) {
        acc[c] += __shfl_xor(acc[c], 1, 16);
        acc[c] += __shfl_xor(acc[c], 2, 16);
        acc[c] += __shfl_xor(acc[c], 4, 16);
        acc[c] += __shfl_xor(acc[c], 8, 16);
    }
    if (valid) {
        if (ksub < 8) asrc[n * 8 + ksub] = acc[ksub];
        else          adst[n * 8 + (ksub - 8)] = acc[ksub];
    }
}

// softmax layer1: pass A gathers el -> stores into aE + online (m,s);
// pass B reads aE SEQUENTIALLY and overwrites with normalized exp.
// wave per node; lane = (j0 = lane>>3, head h = lane&7)
__global__ __launch_bounds__(256) void k_sm1(
    const int* __restrict__ rs, const int* __restrict__ csr_src,
    const float* __restrict__ asrc, const float* __restrict__ adst,
    float* __restrict__ aE, int N)
{
    int node = blockIdx.x * 4 + (threadIdx.x >> 6);
    if (node >= N) return;
    int lane = threadIdx.x & 63;
    int h = lane & 7, j0 = lane >> 3;
    int base = rs[node], deg = rs[node + 1] - base;
    float ad = adst[node * 8 + h];
    float m = -1e30f, s = 0.f;
    for (int j = j0; j < deg; j += 8) {
        int src = csr_src[base + j];
        float el = asrc[src * 8 + h] + ad;
        el = el >= 0.f ? el : NEG_SLOPE * el;
        aE[(size_t)(base + j) * 8 + h] = el;
        if (el > m) { s = s * __expf(m - el) + 1.f; m = el; }
        else        { s += __expf(el - m); }
    }
#pragma unroll
    for (int off = 8; off < 64; off <<= 1) {
        float m2 = __shfl_xor(m, off, 64);
        float s2 = __shfl_xor(s, off, 64);
        float M = fmaxf(m, m2);
        s = s * __expf(m - M) + s2 * __expf(m2 - M);
        m = M;
    }
    float inv = 1.f / (s + 1e-16f);
    for (int j = j0; j < deg; j += 8) {
        float el = aE[(size_t)(base + j) * 8 + h];
        aE[(size_t)(base + j) * 8 + h] = __expf(el - m) * inv;
    }
}

// ===== fused: x-space aggregate (wave per node) + per-head GEMM + bias + ELU =====
// phase 1: wave m = node n0+m; lane = k; acc[8] = all heads.
//   csr_src/aE addresses are WAVE-UNIFORM -> plain loads let the compiler use
//   the scalar path (s_load dual-issues with VALU; FMA takes 1 SGPR operand).
//   No shfl broadcast needed. 2 edges per iteration for load overlap.
// phase 2: b128 broadcast zs reads, k4 loop NOT unrolled (R11-proven, 28 VGPR).
//   (full-unroll float4 spills: R5, R8 — do not reintroduce.)
#define NPB 8
__global__ __launch_bounds__(512) void k_agg_gemm1(
    const int* __restrict__ rs, const int* __restrict__ csr_src,
    const float* __restrict__ aE, const float* __restrict__ x,
    const float* __restrict__ W1, const float* __restrict__ b1,
    bf16* __restrict__ y, int N)
{
    __shared__ float zs[NPB][512];   // 16 KB
    int t = threadIdx.x;
    int wave = t >> 6, lane = t & 63;
    int n = blockIdx.x * NPB + wave;

    if (n < N) {
        int base = rs[n], deg = rs[n + 1] - base;
        float acc[8];
#pragma unroll
        for (int h = 0; h < 8; ++h) acc[h] = 0.f;
        int j = 0;
        for (; j + 1 < deg; j += 2) {
            int s0 = csr_src[base + j];
            int s1 = csr_src[base + j + 1];
            float xv0 = x[(size_t)s0 * 64 + lane];
            float xv1 = x[(size_t)s1 * 64 + lane];
            const float4* ap0 = (const float4*)(aE + (size_t)(base + j) * 8);
            const float4* ap1 = (const float4*)(aE + (size_t)(base + j + 1) * 8);
            float4 a0 = ap0[0], a1 = ap0[1];
            float4 b0 = ap1[0], b1v = ap1[1];
            acc[0] += a0.x * xv0 + b0.x * xv1;
            acc[1] += a0.y * xv0 + b0.y * xv1;
            acc[2] += a0.z * xv0 + b0.z * xv1;
            acc[3] += a0.w * xv0 + b0.w * xv1;
            acc[4] += a1.x * xv0 + b1v.x * xv1;
            acc[5] += a1.y * xv0 + b1v.y * xv1;
            acc[6] += a1.z * xv0 + b1v.z * xv1;
            acc[7] += a1.w * xv0 + b1v.w * xv1;
        }
        if (j < deg) {
            int s0 = csr_src[base + j];
            float xv0 = x[(size_t)s0 * 64 + lane];
            const float4* ap0 = (const float4*)(aE + (size_t)(base + j) * 8);
            float4 a0 = ap0[0], a1 = ap0[1];
            acc[0] += a0.x * xv0; acc[1] += a0.y * xv0;
            acc[2] += a0.z * xv0; acc[3] += a0.w * xv0;
            acc[4] += a1.x * xv0; acc[5] += a1.y * xv0;
            acc[6] += a1.z * xv0; acc[7] += a1.w * xv0;
        }
#pragma unroll
        for (int h = 0; h < 8; ++h) zs[wave][h * 64 + lane] = acc[h];
    } else {
#pragma unroll
        for (int h = 0; h < 8; ++h) zs[wave][h * 64 + lane] = 0.f;
    }
    __syncthreads();

    // phase 2: y[n0+m][t] = elu( sum_k zs[m][h*64+k] * W1[k*512+t] + b1[t] ), h = t>>6
    int n0 = blockIdx.x * NPB;
    int h = t >> 6;
    float acc2[NPB];
#pragma unroll
    for (int m = 0; m < NPB; ++m) acc2[m] = 0.f;
#pragma unroll 1
    for (int k4 = 0; k4 < 16; ++k4) {
        int k = k4 * 4;
        float w0 = W1[(k + 0) * 512 + t];
        float w1 = W1[(k + 1) * 512 + t];
        float w2 = W1[(k + 2) * 512 + t];
        float w3 = W1[(k + 3) * 512 + t];
#pragma unroll
        for (int m = 0; m < NPB; ++m) {
            float4 zv = *(const float4*)&zs[m][h * 64 + k];
            acc2[m] += zv.x * w0 + zv.y * w1 + zv.z * w2 + zv.w * w3;
        }
    }
    float bias = b1[t];
#pragma unroll
    for (int m = 0; m < NPB; ++m) {
        int nn = n0 + m;
        if (nn < N) {
            float v = acc2[m] + bias;
            v = v > 0.f ? v : __expf(v) - 1.f;
            y[(size_t)nn * 512 + t] = __float2bfloat16(v);
        }
    }
}

// ================= Layer 2 =================
// h2 = y @ W2 (+ fused attention dots). 512 thr = 8 waves x 4 nodes x 16 lanes.
// 64 nodes per block (2 passes) to amortize W2 staging; W2t XOR-swizzled.
__global__ __launch_bounds__(512) void k_gemm2(
    const bf16* __restrict__ y, const float* __restrict__ W2,
    const float* __restrict__ a_src2, const float* __restrict__ a_dst2,
    float* __restrict__ h2, float* __restrict__ asrc, float* __restrict__ adst, int N)
{
    __shared__ float W2t[17][512];
    __shared__ float a2s[34];
    int t = threadIdx.x;
    for (int i = t; i < 17 * 512; i += 512) {
        int c = i >> 9, k = i & 511;
        W2t[c][SWZ(k)] = W2[k * 17 + c];
    }
    if (t < 17) a2s[t] = a_src2[t];
    else if (t < 34) a2s[t] = a_dst2[t - 17];
    __syncthreads();

    int wave = t >> 6, lane = t & 63;
    int nsub = lane >> 4, ksub = lane & 15;
    int kx = ksub & 7;

#pragma unroll
    for (int pass = 0; pass < 2; ++pass) {
        int n = blockIdx.x * 64 + pass * 32 + wave * 4 + nsub;
        bool valid = (n < N);

        float yk[32];
        if (valid) {
            const ushort8* yr = (const ushort8*)(y + (size_t)n * 512 + ksub * 32);
#pragma unroll
            for (int v = 0; v < 4; ++v) {
                ushort8 u = yr[v];
#pragma unroll
                for (int j = 0; j < 8; ++j) yk[v * 8 + j] = bf2f(u[j]);
            }
        } else {
#pragma unroll
            for (int i = 0; i < 32; ++i) yk[i] = 0.f;
        }

        float acc[17];
#pragma unroll
        for (int c = 0; c < 17; ++c) {
            float a = 0.f;
#pragma unroll
            for (int v = 0; v < 8; ++v) {
                // physical chunk (v ^ kx) holds logical k-chunk v
                const float4 w = *(const float4*)&W2t[c][ksub * 32 + ((v ^ kx) << 2)];
                a += yk[v * 4 + 0] * w.x + yk[v * 4 + 1] * w.y
                   + yk[v * 4 + 2] * w.z + yk[v * 4 + 3] * w.w;
            }
            acc[c] = a;
        }
#pragma unroll
        for (int c = 0; c < 17; ++c) {
            acc[c] += __shfl_xor(acc[c], 1, 16);
            acc[c] += __shfl_xor(acc[c], 2, 16);
            acc[c] += __shfl_xor(acc[c], 4, 16);
            acc[c] += __shfl_xor(acc[c], 8, 16);
        }
        if (valid) {
            if (ksub < 16) h2[(size_t)n * 17 + ksub] = acc[ksub];
            if (ksub == 0) h2[(size_t)n * 17 + 16] = acc[16];
            if (ksub == 1) {
                float s = 0.f;
#pragma unroll
                for (int c = 0; c < 17; ++c) s += acc[c] * a2s[c];
                asrc[n] = s;
            }
            if (ksub == 2) {
                float d = 0.f;
#pragma unroll
                for (int c = 0; c < 17; ++c) d += acc[c] * a2s[17 + c];
                adst[n] = d;
            }
        }
    }
}

// ===== fused layer2 softmax + aggregate + bias + log_softmax =====
// wave per node. pass A: all 64 lanes online (m,s) over edges.
// pass B: lane = (jsub = lane>>5, c = lane&31); alpha recomputed inline.
__global__ __launch_bounds__(256) void k_out(
    const int* __restrict__ rs, const int* __restrict__ csr_src,
    const float* __restrict__ asrc, const float* __restrict__ adst,
    const float* __restrict__ h2,
    const float* __restrict__ b2, float* __restrict__ out, int N)
{
    int node = blockIdx.x * 4 + (threadIdx.x >> 6);
    if (node >= N) return;
    int lane = threadIdx.x & 63;
    int base = rs[node], deg = rs[node + 1] - base;
    float ad = adst[node];

    // pass A: online (m,s)
    float m = -1e30f, s = 0.f;
    for (int j = lane; j < deg; j += 64) {
        float el = asrc[csr_src[base + j]] + ad;
        el = el >= 0.f ? el : NEG_SLOPE * el;
        if (el > m) { s = s * __expf(m - el) + 1.f; m = el; }
        else        { s += __expf(el - m); }
    }
#pragma unroll
    for (int off = 1; off < 64; off <<= 1) {
        float m2 = __shfl_xor(m, off, 64);
        float s2 = __shfl_xor(s, off, 64);
        float M = fmaxf(m, m2);
        s = s * __expf(m - M) + s2 * __expf(m2 - M);
        m = M;
    }
    float inv = 1.f / (s + 1e-16f);

    // pass B: aggregate with inline alpha
    int c = lane & 31, jsub = lane >> 5;
    float acc = 0.f;
    if (c < 17) {
        for (int p = base + jsub; p < base + deg; p += 2) {
            int src = csr_src[p];
            float el = asrc[src] + ad;
            el = el >= 0.f ? el : NEG_SLOPE * el;
            float alpha = __expf(el - m) * inv;
            acc += alpha * h2[(size_t)src * 17 + c];
        }
    }
    acc += __shfl_xor(acc, 32, 64);  // combine the two edge halves
    float logit = (c < 17) ? acc + b2[c] : -1e30f;
    float mm = logit;
#pragma unroll
    for (int off = 1; off < 32; off <<= 1) mm = fmaxf(mm, __shfl_xor(mm, off, 32));
    float p = (c < 17) ? __expf(logit - mm) : 0.f;
    float ssum = p;
#pragma unroll
    for (int off = 1; off < 32; off <<= 1) ssum += __shfl_xor(ssum, off, 32);
    if (c < 17 && jsub == 0) out[(size_t)node * 17 + c] = logit - mm - logf(ssum);
}

extern "C" void kernel_launch(void* const* d_in, const int* in_sizes, int n_in,
                              void* d_out, int out_size, void* d_ws, size_t ws_size,
                              hipStream_t stream)
{
    const float* x      = (const float*)d_in[0];
    const int*   ei     = (const int*)d_in[1];
    const float* W1     = (const float*)d_in[2];
    const float* asrc1w = (const float*)d_in[3];
    const float* adst1w = (const float*)d_in[4];
    const float* b1     = (const float*)d_in[5];
    const float* W2     = (const float*)d_in[6];
    const float* asrc2w = (const float*)d_in[7];
    const float* adst2w = (const float*)d_in[8];
    const float* b2     = (const float*)d_in[9];
    float* out = (float*)d_out;

    const int N = in_sizes[0] / 64;
    const int E = in_sizes[1] / 2;
    const int Etot = N + E;

    // workspace layout
    float* ws = (float*)d_ws;
    size_t o = 0;
    bf16*  y      = (bf16*)(ws + o); o += (size_t)N * 256;   // N*512 bf16
    float* wboth  = ws + o; o += 1024;
    float* asrc1  = ws + o; o += (size_t)N * 8;
    float* adst1  = ws + o; o += (size_t)N * 8;
    float* aE1    = ws + o; o += (size_t)Etot * 8;
    float* h2     = ws + o; o += (size_t)N * 17;
    float* asrc2  = ws + o; o += (size_t)N;
    float* adst2  = ws + o; o += (size_t)N;
    int* deg      = (int*)(ws + o); o += (size_t)N;
    int* cur      = (int*)(ws + o); o += (size_t)N;
    int* rs       = (int*)(ws + o); o += (size_t)N + 1;
    int* csr_src  = (int*)(ws + o); o += (size_t)Etot;

    hipMemsetAsync(deg, 0, (size_t)N * 4, stream);
    hipMemsetAsync(cur, 0, (size_t)N * 4, stream);

    // CSR build
    {
        int blk = 256, g = (Etot + blk - 1) / blk;
        k_hist<<<g, blk, 0, stream>>>(ei, E, Etot, deg);
        k_scan<<<1, 1024, 0, stream>>>(deg, rs, N);
        k_fill<<<g, blk, 0, stream>>>(ei, E, Etot, rs, cur, csr_src);
    }

    // layer 1
    k_prew<<<1, 512, 0, stream>>>(W1, asrc1w, adst1w, wboth);
    k_alpha1n<<<(N + 15) / 16, 256, 0, stream>>>(x, wboth, asrc1, adst1, N);
    k_sm1<<<(N + 3) / 4, 256, 0, stream>>>(rs, csr_src, asrc1, adst1, aE1, N);
    k_agg_gemm1<<<(N + NPB - 1) / NPB, 512, 0, stream>>>(rs, csr_src, aE1, x, W1, b1, y, N);

    // layer 2
    k_gemm2<<<(N + 63) / 64, 512, 0, stream>>>(y, W2, asrc2w, adst2w, h2, asrc2, adst2, N);
    k_out<<<(N + 3) / 4, 256, 0, stream>>>(rs, csr_src, asrc2, adst2, h2, b2, out, N);
}